// Round 2
// baseline (174.389 us; speedup 1.0000x reference)
//
#include <hip/hip_runtime.h>
#include <stdint.h>

#define N_ROWS 4096
#define Z_DIM  2048
#define TOT    8192           // 2N rows of reps
#define RBYTES (Z_DIM / 2)    // 1024 B per fp4 row
#define BKE    128            // K elements per staging step
#define KBYT   (BKE / 2)      // 64 B per row per step
#define NITER  (Z_DIM / BKE)  // 16
#define BM     256            // tile rows
#define BN     256            // tile cols
#define NT32   (TOT / BM)     // 32 tiles
#define NBLK   528            // upper triangle incl. diagonal
#define OPB    (BM * KBYT)    // 16384 B per operand per buffer
#define BUFB   (2 * OPB)      // 32768 B per buffer (A + B)
#define INV_T  2.0f           // 1/temperature
#define SCL4   64.0f          // fp4 pre-scale; logits = acc * INV_T / SCL4^2

typedef __attribute__((ext_vector_type(4))) int   intx4;
typedef __attribute__((ext_vector_type(8))) int   intx8;
typedef __attribute__((ext_vector_type(4))) float floatx4;

#define GLOAD16(g, l)                                                   \
    __builtin_amdgcn_global_load_lds(                                   \
        (const __attribute__((address_space(1))) unsigned int*)(g),     \
        (__attribute__((address_space(3))) unsigned int*)(l), 16, 0, 0)

// branchless f32 -> fp4 e2m1 code (round to nearest level)
__device__ __forceinline__ unsigned int f2fp4(float v) {
    float a = fabsf(v);
    unsigned int c = (a >= 0.25f) + (a >= 0.75f) + (a >= 1.25f) + (a >= 1.75f)
                   + (a >= 2.5f)  + (a >= 3.5f)  + (a >= 5.0f);
    return c | (v < 0.f ? 8u : 0u);
}

// ---------------- kernel 1: row-normalize to fp4(e2m1, x64), pos, zero rowsum
__global__ __launch_bounds__(256) void normalize_kernel(
    const float* __restrict__ z1, const float* __restrict__ z2,
    unsigned char* __restrict__ reps, float* __restrict__ pos,
    float* __restrict__ rowsum)
{
    const int row  = blockIdx.x;          // 0..4095
    const int tid  = threadIdx.x;         // 0..255, 8 floats each
    const int lane = tid & 63, wave = tid >> 6;

    if (row < TOT / 256) rowsum[row * 256 + tid] = 0.f;   // fold in memset

    const float4* p1 = (const float4*)(z1 + (size_t)row * Z_DIM);
    const float4* p2 = (const float4*)(z2 + (size_t)row * Z_DIM);
    float4 x0 = p1[tid * 2], x1 = p1[tid * 2 + 1];
    float4 y0 = p2[tid * 2], y1 = p2[tid * 2 + 1];

    float s1 = x0.x*x0.x + x0.y*x0.y + x0.z*x0.z + x0.w*x0.w
             + x1.x*x1.x + x1.y*x1.y + x1.z*x1.z + x1.w*x1.w;
    float s2 = y0.x*y0.x + y0.y*y0.y + y0.z*y0.z + y0.w*y0.w
             + y1.x*y1.x + y1.y*y1.y + y1.z*y1.z + y1.w*y1.w;
    float dd = x0.x*y0.x + x0.y*y0.y + x0.z*y0.z + x0.w*y0.w
             + x1.x*y1.x + x1.y*y1.y + x1.z*y1.z + x1.w*y1.w;

    #pragma unroll
    for (int m = 1; m < 64; m <<= 1) {
        s1 += __shfl_xor(s1, m);
        s2 += __shfl_xor(s2, m);
        dd += __shfl_xor(dd, m);
    }
    __shared__ float red[3][4];
    if (lane == 0) { red[0][wave] = s1; red[1][wave] = s2; red[2][wave] = dd; }
    __syncthreads();
    s1 = red[0][0] + red[0][1] + red[0][2] + red[0][3];
    s2 = red[1][0] + red[1][1] + red[1][2] + red[1][3];
    dd = red[2][0] + red[2][1] + red[2][2] + red[2][3];

    const float inv1 = rsqrtf(s1), inv2 = rsqrtf(s2);
    if (tid == 0) {
        float p = dd * inv1 * inv2 * INV_T;   // pos in full fp32 precision
        pos[row] = p;
        pos[row + N_ROWS] = p;
    }

    const float a = inv1 * SCL4, b = inv2 * SCL4;
    unsigned int pa =  f2fp4(x0.x * a)        | (f2fp4(x0.y * a) << 4)
                    | (f2fp4(x0.z * a) << 8)  | (f2fp4(x0.w * a) << 12)
                    | (f2fp4(x1.x * a) << 16) | (f2fp4(x1.y * a) << 20)
                    | (f2fp4(x1.z * a) << 24) | (f2fp4(x1.w * a) << 28);
    unsigned int pb =  f2fp4(y0.x * b)        | (f2fp4(y0.y * b) << 4)
                    | (f2fp4(y0.z * b) << 8)  | (f2fp4(y0.w * b) << 12)
                    | (f2fp4(y1.x * b) << 16) | (f2fp4(y1.y * b) << 20)
                    | (f2fp4(y1.z * b) << 24) | (f2fp4(y1.w * b) << 28);
    *(unsigned int*)(reps + (size_t)row * RBYTES + tid * 4) = pa;
    *(unsigned int*)(reps + (size_t)(N_ROWS + row) * RBYTES + tid * 4) = pb;
}

// ---------------- kernel 2: 256x256-tile S = reps@reps^T, MX-fp4 K=128 ------
// 8 waves (2 row-halves x 4 col-quarters), wave tile 128x64:
// 12 ds_read_b128 : 32 MFMA per K-step -> MFMA is the longest pipe.
// Per K-step: 4 phases, phase p = { ds_read A-frags fi=2p,2p+1 (+ all B at
// p=0) | issue GLOAD batch p of step i+2 | s_barrier | setprio(1) 8 MFMA
// setprio(0) }.  Triple-buffered LDS (3 x 32 KiB); one counted
// `s_waitcnt vmcnt(4)` per K-step (leaves next step's 4 batches in flight),
// never drains to 0 mid-loop.
// LDS swizzle (2-way = free): 16B slot s of row r holds global chunk
// s ^ ((r>>1)&3); read chunk `quad` of row r at slot quad ^ ((r>>1)&3).
// Source is pre-swizzled so global_load_lds dest stays linear (rule 21).
// Coverage: blocks (ri <= cj); count only c > r on diag blocks; every exp
// credits BOTH rowsum[r] (srow) and rowsum[c] (scol).
__global__ __launch_bounds__(512, 2) void simclr_gemm(
    const unsigned char* __restrict__ reps, float* __restrict__ rowsum)
{
    __shared__ __align__(16) unsigned char L[3 * BUFB];   // 96 KiB

    // linear block id -> (ri, cj), ri <= cj < 32; base(ri) = ri*32 - ri(ri-1)/2
    const int t = blockIdx.x;
    int ri = (int)((65.0f - sqrtf(4225.0f - 8.0f * (float)t)) * 0.5f);
    while (ri > 0  && ri * 32 - ri * (ri - 1) / 2 > t) --ri;
    while (ri < 31 && (ri + 1) * 32 - (ri + 1) * ri / 2 <= t) ++ri;
    const int cj = ri + (t - (ri * 32 - ri * (ri - 1) / 2));
    const bool diag = (ri == cj);
    const int row0 = ri * BM, col0 = cj * BN;

    const int tid  = threadIdx.x;
    const int lane = tid & 63, wave = tid >> 6;
    const int wr = wave >> 2, wc = wave & 3;     // 2x4 waves over 256x256
    const int quad = lane >> 4, l16 = lane & 15;

    // on diag blocks, waves whose 64-col range is entirely below their
    // 128-row range are dead (fully masked): skip reads/MFMA/epilogue,
    // keep staging + barriers (vmcnt counts must match across waves).
    const bool alive = !(diag && wr == 1 && wc < 2);

    // staging: 4 batches/step of 512 x 16B chunks (1 GLOAD/thread/batch).
    // batch q: rows rl = (q&1)*128 + tid/4 of operand (q<2 ? A : B);
    // LDS dest (linear): q*8192 + tid*16; source chunk pre-swizzled.
    const unsigned char* gsrc[4];
    #pragma unroll
    for (int q = 0; q < 4; ++q) {
        const int rl = (q & 1) * 128 + (tid >> 2);
        const int g  = (tid & 3) ^ ((rl >> 1) & 3);
        const int rowg = (q < 2 ? row0 : col0) + rl;
        gsrc[q] = reps + (size_t)rowg * RBYTES + g * 16;
    }
    const int dstoff = tid * 16;
    const int swz = (quad ^ ((l16 >> 1) & 3)) << 4;   // read-side slot XOR

    floatx4 acc[8][4];
    #pragma unroll
    for (int i = 0; i < 8; ++i)
        #pragma unroll
        for (int j = 0; j < 4; ++j)
            acc[i][j] = floatx4{0.f, 0.f, 0.f, 0.f};

    // prologue: stage steps 0 and 1 (8 loads/thread in flight)
    #pragma unroll
    for (int q = 0; q < 4; ++q) GLOAD16(gsrc[q],        &L[0 * BUFB + q * 8192 + dstoff]);
    #pragma unroll
    for (int q = 0; q < 4; ++q) GLOAD16(gsrc[q] + KBYT, &L[1 * BUFB + q * 8192 + dstoff]);

    int cur = 0;
    #pragma unroll 1
    for (int i = 0; i < NITER; ++i) {
        // complete step i's 4 batches; leave step i+1's 4 in flight
        if (i + 1 < NITER) asm volatile("s_waitcnt vmcnt(4)" ::: "memory");
        else               asm volatile("s_waitcnt vmcnt(0)" ::: "memory");
        __builtin_amdgcn_s_barrier();

        int pf = cur + 2; if (pf >= 3) pf -= 3;
        const bool st = (i + 2 < NITER);
        const size_t ko = (size_t)(i + 2) * KBYT;
        const unsigned char* Ab = &L[cur * BUFB];
        const unsigned char* Bb = Ab + OPB;
        unsigned char* Lp = &L[pf * BUFB];

        intx8 b8[4];

#define PHASE(p)                                                             \
        {                                                                    \
            intx4 a0v, a1v;                                                  \
            if (alive) {                                                     \
                if (p == 0) {                                                \
                    _Pragma("unroll")                                        \
                    for (int j = 0; j < 4; ++j) {                            \
                        const int rb = wc * 64 + j * 16 + l16;               \
                        intx4 bv = *(const intx4*)(Bb + rb * KBYT + swz);    \
                        b8[j] = intx8{bv[0], bv[1], bv[2], bv[3], 0,0,0,0};  \
                    }                                                        \
                }                                                            \
                a0v = *(const intx4*)(Ab + (wr*128 + (2*(p))  *16 + l16)*KBYT + swz); \
                a1v = *(const intx4*)(Ab + (wr*128 + (2*(p)+1)*16 + l16)*KBYT + swz); \
            }                                                                \
            if (st) GLOAD16(gsrc[p] + ko, Lp + (p) * 8192 + dstoff);         \
            __builtin_amdgcn_s_barrier();                                    \
            if (alive) {                                                     \
                intx8 a80 = intx8{a0v[0], a0v[1], a0v[2], a0v[3], 0,0,0,0};  \
                intx8 a81 = intx8{a1v[0], a1v[1], a1v[2], a1v[3], 0,0,0,0};  \
                __builtin_amdgcn_s_setprio(1);                               \
                _Pragma("unroll")                                            \
                for (int j = 0; j < 4; ++j)                                  \
                    acc[2*(p)][j] =                                          \
                        __builtin_amdgcn_mfma_scale_f32_16x16x128_f8f6f4(    \
                            a80, b8[j], acc[2*(p)][j],                       \
                            4, 4, 0, 0x7F7F7F7Fu, 0, 0x7F7F7F7Fu);           \
                _Pragma("unroll")                                            \
                for (int j = 0; j < 4; ++j)                                  \
                    acc[2*(p)+1][j] =                                        \
                        __builtin_amdgcn_mfma_scale_f32_16x16x128_f8f6f4(    \
                            a81, b8[j], acc[2*(p)+1][j],                     \
                            4, 4, 0, 0x7F7F7F7Fu, 0, 0x7F7F7F7Fu);           \
                __builtin_amdgcn_s_setprio(0);                               \
            }                                                                \
        }

        PHASE(0)
        PHASE(1)
        PHASE(2)
        PHASE(3)
#undef PHASE

        cur = (cur == 2) ? 0 : cur + 1;
    }

    // Epilogue: C/D layout col = l16, row = quad*4 + reg.
    // Mask r >= c on diag blocks only; credit srow (row r) AND scol (row c).
    const float descale = INV_T / (SCL4 * SCL4);   // 1/2048
    if (alive) {
        float scol[4] = {0.f, 0.f, 0.f, 0.f};
        #pragma unroll
        for (int fi = 0; fi < 8; ++fi) {
            const int rbase = row0 + wr * 128 + fi * 16 + quad * 4;
            float srow[4] = {0.f, 0.f, 0.f, 0.f};
            #pragma unroll
            for (int j = 0; j < 4; ++j) {
                const int c = col0 + wc * 64 + j * 16 + l16;
                #pragma unroll
                for (int rr = 0; rr < 4; ++rr) {
                    float e = (!diag || c > rbase + rr)
                            ? __expf(acc[fi][j][rr] * descale) : 0.f;
                    srow[rr] += e;
                    scol[j]  += e;
                }
            }
            #pragma unroll
            for (int rr = 0; rr < 4; ++rr) {
                #pragma unroll
                for (int m = 1; m < 16; m <<= 1)
                    srow[rr] += __shfl_xor(srow[rr], m);
            }
            if (l16 == 0) {
                #pragma unroll
                for (int rr = 0; rr < 4; ++rr)
                    atomicAdd(&rowsum[rbase + rr], srow[rr]);
            }
        }
        #pragma unroll
        for (int j = 0; j < 4; ++j) {
            scol[j] += __shfl_xor(scol[j], 16);
            scol[j] += __shfl_xor(scol[j], 32);
        }
        if (quad == 0) {
            #pragma unroll
            for (int j = 0; j < 4; ++j)
                atomicAdd(&rowsum[col0 + wc * 64 + j * 16 + l16], scol[j]);
        }
    }
}

// ---------------- kernel 3: mean(log(rowsum) - pos) ----------------
__global__ __launch_bounds__(1024) void finalize_kernel(
    const float* __restrict__ rowsum, const float* __restrict__ pos,
    float* __restrict__ out)
{
    const int tid = threadIdx.x;
    const int lane = tid & 63, wave = tid >> 6;
    float s = 0.f;
    for (int r = tid; r < TOT; r += 1024) s += logf(rowsum[r]) - pos[r];
    #pragma unroll
    for (int m = 1; m < 64; m <<= 1) s += __shfl_xor(s, m);
    __shared__ float red[16];
    if (lane == 0) red[wave] = s;
    __syncthreads();
    if (tid == 0) {
        float t = 0.f;
        #pragma unroll
        for (int w = 0; w < 16; ++w) t += red[w];
        out[0] = t * (1.0f / TOT);
    }
}

extern "C" void kernel_launch(void* const* d_in, const int* in_sizes, int n_in,
                              void* d_out, int out_size, void* d_ws, size_t ws_size,
                              hipStream_t stream)
{
    const float* z1 = (const float*)d_in[0];
    const float* z2 = (const float*)d_in[1];
    float* out = (float*)d_out;

    char* w = (char*)d_ws;
    unsigned char* reps = (unsigned char*)w;                 // 8 MiB fp4 [8192][1024B]
    float* pos    = (float*)(w + (size_t)TOT * RBYTES);      // 32 KiB
    float* rowsum = pos + TOT;                               // 32 KiB

    normalize_kernel<<<N_ROWS, 256, 0, stream>>>(z1, z2, reps, pos, rowsum);
    simclr_gemm<<<NBLK, 512, 0, stream>>>(reps, rowsum);
    finalize_kernel<<<1, 1024, 0, stream>>>(rowsum, pos, out);
}

// Round 3
// 156.784 us; speedup vs baseline: 1.1123x; 1.1123x over previous
//
#include <hip/hip_runtime.h>
#include <stdint.h>

#define N_ROWS 4096
#define Z_DIM  2048
#define TOT    8192           // 2N rows of reps
#define TILE   128
#define RBYTES (Z_DIM / 2)    // 1024 B per fp4 row
#define BKE    128            // K elements per staging round
#define KBYT   (BKE / 2)      // 64 B per row per staging round
#define NITER  (Z_DIM / BKE)  // 16
#define NT     (TOT / TILE)   // 64 tile-columns
#define NBLK   (NT * (NT + 1) / 2)   // 2080 triangular blocks
#define INV_T  2.0f           // 1/temperature
#define SCL4   64.0f          // fp4 pre-scale; logits = acc * INV_T / SCL4^2

typedef __attribute__((ext_vector_type(4))) int   intx4;
typedef __attribute__((ext_vector_type(8))) int   intx8;
typedef __attribute__((ext_vector_type(4))) float floatx4;

#define GLOAD16(g, l)                                                   \
    __builtin_amdgcn_global_load_lds(                                   \
        (const __attribute__((address_space(1))) unsigned int*)(g),     \
        (__attribute__((address_space(3))) unsigned int*)(l), 16, 0, 0)

// branchless f32 -> fp4 e2m1 code (round to nearest level)
// levels: 0,0.5,1,1.5,2,3,4,6 ; thresholds at midpoints
__device__ __forceinline__ unsigned int f2fp4(float v) {
    float a = fabsf(v);
    unsigned int c = (a >= 0.25f) + (a >= 0.75f) + (a >= 1.25f) + (a >= 1.75f)
                   + (a >= 2.5f)  + (a >= 3.5f)  + (a >= 5.0f);
    return c | (v < 0.f ? 8u : 0u);
}

// ---------------- kernel 1: row-normalize to fp4(e2m1, x64), pos, zero rowsum
__global__ __launch_bounds__(256) void normalize_kernel(
    const float* __restrict__ z1, const float* __restrict__ z2,
    unsigned char* __restrict__ reps, float* __restrict__ pos,
    float* __restrict__ rowsum)
{
    const int row  = blockIdx.x;          // 0..4095
    const int tid  = threadIdx.x;         // 0..255, 8 floats each
    const int lane = tid & 63, wave = tid >> 6;

    if (row < TOT / 256) rowsum[row * 256 + tid] = 0.f;   // fold in memset

    const float4* p1 = (const float4*)(z1 + (size_t)row * Z_DIM);
    const float4* p2 = (const float4*)(z2 + (size_t)row * Z_DIM);
    float4 x0 = p1[tid * 2], x1 = p1[tid * 2 + 1];
    float4 y0 = p2[tid * 2], y1 = p2[tid * 2 + 1];

    float s1 = x0.x*x0.x + x0.y*x0.y + x0.z*x0.z + x0.w*x0.w
             + x1.x*x1.x + x1.y*x1.y + x1.z*x1.z + x1.w*x1.w;
    float s2 = y0.x*y0.x + y0.y*y0.y + y0.z*y0.z + y0.w*y0.w
             + y1.x*y1.x + y1.y*y1.y + y1.z*y1.z + y1.w*y1.w;
    float dd = x0.x*y0.x + x0.y*y0.y + x0.z*y0.z + x0.w*y0.w
             + x1.x*y1.x + x1.y*y1.y + x1.z*y1.z + x1.w*y1.w;

    #pragma unroll
    for (int m = 1; m < 64; m <<= 1) {
        s1 += __shfl_xor(s1, m);
        s2 += __shfl_xor(s2, m);
        dd += __shfl_xor(dd, m);
    }
    __shared__ float red[3][4];
    if (lane == 0) { red[0][wave] = s1; red[1][wave] = s2; red[2][wave] = dd; }
    __syncthreads();
    s1 = red[0][0] + red[0][1] + red[0][2] + red[0][3];
    s2 = red[1][0] + red[1][1] + red[1][2] + red[1][3];
    dd = red[2][0] + red[2][1] + red[2][2] + red[2][3];

    const float inv1 = rsqrtf(s1), inv2 = rsqrtf(s2);
    if (tid == 0) {
        float p = dd * inv1 * inv2 * INV_T;   // pos in full fp32 precision
        pos[row] = p;
        pos[row + N_ROWS] = p;
    }

    // fp4 encode of (normalized * 64): sigma ~1.4, range to ~6 (rare clip).
    // elem k -> byte k/2, LOW nibble = even k.
    const float a = inv1 * SCL4, b = inv2 * SCL4;
    unsigned int pa =  f2fp4(x0.x * a)        | (f2fp4(x0.y * a) << 4)
                    | (f2fp4(x0.z * a) << 8)  | (f2fp4(x0.w * a) << 12)
                    | (f2fp4(x1.x * a) << 16) | (f2fp4(x1.y * a) << 20)
                    | (f2fp4(x1.z * a) << 24) | (f2fp4(x1.w * a) << 28);
    unsigned int pb =  f2fp4(y0.x * b)        | (f2fp4(y0.y * b) << 4)
                    | (f2fp4(y0.z * b) << 8)  | (f2fp4(y0.w * b) << 12)
                    | (f2fp4(y1.x * b) << 16) | (f2fp4(y1.y * b) << 20)
                    | (f2fp4(y1.z * b) << 24) | (f2fp4(y1.w * b) << 28);
    *(unsigned int*)(reps + (size_t)row * RBYTES + tid * 4) = pa;
    *(unsigned int*)(reps + (size_t)(N_ROWS + row) * RBYTES + tid * 4) = pb;
}

// ---------------- kernel 2: triangular S = reps@reps^T, MX-fp4 K=128 --------
// Round-0 structure (128x128 tile, 2x2 waves, 4x4 grid of 16x16x128 f8f6f4
// MFMA, dbuf + prefetch-before-MFMA, one __syncthreads per K-step, 32 KiB
// LDS -> 3+ blocks/CU of cross-block overlap).
// ONLY change vs round 0: LDS 16B-chunk swizzle key row&3 -> (row>>1)&3.
// Old key: read XOR used l16&3; even lanes only hit 2 of 4 slot-groups ->
// 4-way bank conflict (measured +4 cyc per ds_read_b128, 4.26M conflict cy).
// New key cycles 0,1,2,3 over even lanes -> 2-way (free). Same involution on
// stage side (pre-swizzled global source, linear LDS dest) per rule 21;
// this exact pair is correctness-verified (round-2 kernel passed with it).
__global__ __launch_bounds__(256) void simclr_gemm(
    const unsigned char* __restrict__ reps, float* __restrict__ rowsum)
{
    __shared__ __align__(16) unsigned char L[2][2][TILE * KBYT];   // 32 KiB

    // decode linear block id -> lower-triangle (r >= c); bi = c, bj = r
    const int t = blockIdx.x;
    int r = (int)((sqrtf(8.0f * (float)t + 1.0f) - 1.0f) * 0.5f);
    while ((r + 1) * (r + 2) / 2 <= t) ++r;
    while (r * (r + 1) / 2 > t) --r;
    const int bi = t - r * (r + 1) / 2;   // <= bj
    const int bj = r;
    const bool diag = (bi == bj);

    const int tid  = threadIdx.x;
    const int lane = tid & 63, wave = tid >> 6;
    const int wr = wave >> 1, wc = wave & 1;       // 2x2 waves over 128x128
    const int quad = lane >> 4, l16 = lane & 15;
    const int sw   = (l16 >> 1) & 3;               // read-side XOR swizzle key
    const int row0 = bi * TILE, col0 = bj * TILE;

    floatx4 acc[4][4];
    #pragma unroll
    for (int i = 0; i < 4; ++i)
        #pragma unroll
        for (int j = 0; j < 4; ++j)
            acc[i][j] = floatx4{0.f, 0.f, 0.f, 0.f};

    // staging: 512 chunks of 16B per operand (128 rows x 4 chunks); thread
    // handles chunks tid and tid+256. LDS slot c holds global chunk
    // ((c&3) ^ (((c>>2)>>1)&3)) of row c>>2.
    const int c0 = tid, c1 = tid + 256;
    const int r0s = c0 >> 2, k0s = (c0 & 3) ^ ((r0s >> 1) & 3);
    const int r1s = c1 >> 2, k1s = (c1 & 3) ^ ((r1s >> 1) & 3);
    const unsigned char* gA0 = reps + (size_t)(row0 + r0s) * RBYTES + k0s * 16;
    const unsigned char* gA1 = reps + (size_t)(row0 + r1s) * RBYTES + k1s * 16;
    const unsigned char* gB0 = reps + (size_t)(col0 + r0s) * RBYTES + k0s * 16;
    const unsigned char* gB1 = reps + (size_t)(col0 + r1s) * RBYTES + k1s * 16;
    const int o0 = c0 * 16, o1 = c1 * 16;

    // prologue: tile 0 -> buffer 0
    GLOAD16(gA0, &L[0][0][o0]);
    GLOAD16(gA1, &L[0][0][o1]);
    GLOAD16(gB0, &L[0][1][o0]);
    GLOAD16(gB1, &L[0][1][o1]);
    __syncthreads();

    for (int i = 0; i < NITER; ++i) {
        if (i + 1 < NITER) {              // prefetch tile i+1 into buf^1
            const size_t ko = (size_t)(i + 1) * KBYT;
            const int buf = (i + 1) & 1;
            GLOAD16(gA0 + ko, &L[buf][0][o0]);
            GLOAD16(gA1 + ko, &L[buf][0][o1]);
            GLOAD16(gB0 + ko, &L[buf][1][o0]);
            GLOAD16(gB1 + ko, &L[buf][1][o1]);
        }
        const unsigned char* Ab = &L[i & 1][0][0];
        const unsigned char* Bb = &L[i & 1][1][0];

        // fragment: 32 fp4 nibbles (elems k=quad*32..+32) = 16 B = 1 b128.
        // FMT=fp4 reads only v[0:3] of the 8-reg operand; upper half zero.
        intx8 af[4], bf[4];
        #pragma unroll
        for (int fi = 0; fi < 4; ++fi) {
            const int ar = (wr * 64 + fi * 16 + l16) * KBYT;
            const int br = (wc * 64 + fi * 16 + l16) * KBYT;
            intx4 av = *(const intx4*)&Ab[ar + ((quad ^ sw) << 4)];
            intx4 bv = *(const intx4*)&Bb[br + ((quad ^ sw) << 4)];
            af[fi] = intx8{av[0], av[1], av[2], av[3], 0, 0, 0, 0};
            bf[fi] = intx8{bv[0], bv[1], bv[2], bv[3], 0, 0, 0, 0};
        }
        #pragma unroll
        for (int fi = 0; fi < 4; ++fi)
            #pragma unroll
            for (int j = 0; j < 4; ++j)
                acc[fi][j] = __builtin_amdgcn_mfma_scale_f32_16x16x128_f8f6f4(
                    af[fi], bf[j], acc[fi][j],
                    4, 4,                      // cbsz=fp4(A), blgp=fp4(B)
                    0, 0x7F7F7F7Fu,            // scale_a = 1.0 (E8M0)
                    0, 0x7F7F7F7Fu);           // scale_b = 1.0
        __syncthreads();
    }

    // Epilogue: C/D layout col = lane&15, row = quad*4 + reg.
    // logit = acc * INV_T / SCL4^2; |logit| <= 2 so plain exp-sum is safe.
    const float descale = INV_T / (SCL4 * SCL4);   // 1/2048
    float scol[4] = {0.f, 0.f, 0.f, 0.f};
    #pragma unroll
    for (int fi = 0; fi < 4; ++fi) {
        const int rbase = row0 + wr * 64 + fi * 16 + quad * 4;
        float srow[4] = {0.f, 0.f, 0.f, 0.f};
        #pragma unroll
        for (int j = 0; j < 4; ++j) {
            const int c = col0 + wc * 64 + j * 16 + l16;
            #pragma unroll
            for (int rr = 0; rr < 4; ++rr) {
                float e = __expf(acc[fi][j][rr] * descale);
                if (diag && (rbase + rr == c)) e = 0.f;  // exclude self-sim
                srow[rr] += e;
                scol[j]  += e;
            }
        }
        #pragma unroll
        for (int rr = 0; rr < 4; ++rr) {
            #pragma unroll
            for (int m = 1; m < 16; m <<= 1) srow[rr] += __shfl_xor(srow[rr], m);
        }
        if (l16 == 0) {
            #pragma unroll
            for (int rr = 0; rr < 4; ++rr)
                atomicAdd(&rowsum[rbase + rr], srow[rr]);
        }
    }
    if (!diag) {   // symmetry credit: column sums -> mirrored rows
        #pragma unroll
        for (int j = 0; j < 4; ++j) {
            scol[j] += __shfl_xor(scol[j], 16);
            scol[j] += __shfl_xor(scol[j], 32);
        }
        if (quad == 0) {
            #pragma unroll
            for (int j = 0; j < 4; ++j)
                atomicAdd(&rowsum[col0 + wc * 64 + j * 16 + l16], scol[j]);
        }
    }
}

// ---------------- kernel 3: mean(log(rowsum) - pos) ----------------
__global__ __launch_bounds__(1024) void finalize_kernel(
    const float* __restrict__ rowsum, const float* __restrict__ pos,
    float* __restrict__ out)
{
    const int tid = threadIdx.x;
    const int lane = tid & 63, wave = tid >> 6;
    float s = 0.f;
    for (int r = tid; r < TOT; r += 1024) s += logf(rowsum[r]) - pos[r];
    #pragma unroll
    for (int m = 1; m < 64; m <<= 1) s += __shfl_xor(s, m);
    __shared__ float red[16];
    if (lane == 0) red[wave] = s;
    __syncthreads();
    if (tid == 0) {
        float t = 0.f;
        #pragma unroll
        for (int w = 0; w < 16; ++w) t += red[w];
        out[0] = t * (1.0f / TOT);
    }
}

extern "C" void kernel_launch(void* const* d_in, const int* in_sizes, int n_in,
                              void* d_out, int out_size, void* d_ws, size_t ws_size,
                              hipStream_t stream)
{
    const float* z1 = (const float*)d_in[0];
    const float* z2 = (const float*)d_in[1];
    float* out = (float*)d_out;

    char* w = (char*)d_ws;
    unsigned char* reps = (unsigned char*)w;                 // 8 MiB fp4 [8192][1024B]
    float* pos    = (float*)(w + (size_t)TOT * RBYTES);      // 32 KiB
    float* rowsum = pos + TOT;                               // 32 KiB

    normalize_kernel<<<N_ROWS, 256, 0, stream>>>(z1, z2, reps, pos, rowsum);
    simclr_gemm<<<NBLK, 256, 0, stream>>>(reps, rowsum);
    finalize_kernel<<<1, 1024, 0, stream>>>(rowsum, pos, out);
}

// Round 4
// 149.059 us; speedup vs baseline: 1.1699x; 1.0518x over previous
//
#include <hip/hip_runtime.h>
#include <stdint.h>

#define N_ROWS 4096
#define Z_DIM  2048
#define TOT    8192           // 2N rows of reps
#define TILE   128
#define RBYTES (Z_DIM / 2)    // 1024 B per fp4 row
#define BKE    128            // K elements per staging round
#define KBYT   (BKE / 2)      // 64 B per row per staging round
#define NITER  (Z_DIM / BKE)  // 16
#define NT     (TOT / TILE)   // 64 tile-columns
#define NBLK   (NT * (NT + 1) / 2)   // 2080 triangular blocks (2080%8==0)
#define INV_T  2.0f           // 1/temperature
#define SCL4   64.0f          // fp4 pre-scale; logits = acc * INV_T / SCL4^2

typedef __attribute__((ext_vector_type(4))) int   intx4;
typedef __attribute__((ext_vector_type(8))) int   intx8;
typedef __attribute__((ext_vector_type(4))) float floatx4;

#define GLOAD16(g, l)                                                   \
    __builtin_amdgcn_global_load_lds(                                   \
        (const __attribute__((address_space(1))) unsigned int*)(g),     \
        (__attribute__((address_space(3))) unsigned int*)(l), 16, 0, 0)

// branchless f32 -> fp4 e2m1 code (round to nearest level)
// levels: 0,0.5,1,1.5,2,3,4,6 ; thresholds at midpoints
__device__ __forceinline__ unsigned int f2fp4(float v) {
    float a = fabsf(v);
    unsigned int c = (a >= 0.25f) + (a >= 0.75f) + (a >= 1.25f) + (a >= 1.75f)
                   + (a >= 2.5f)  + (a >= 3.5f)  + (a >= 5.0f);
    return c | (v < 0.f ? 8u : 0u);
}

// ---------------- kernel 1: row-normalize to fp4(e2m1, x64), pos, zero rowsum
__global__ __launch_bounds__(256) void normalize_kernel(
    const float* __restrict__ z1, const float* __restrict__ z2,
    unsigned char* __restrict__ reps, float* __restrict__ pos,
    float* __restrict__ rowsum)
{
    const int row  = blockIdx.x;          // 0..4095
    const int tid  = threadIdx.x;         // 0..255, 8 floats each
    const int lane = tid & 63, wave = tid >> 6;

    if (row < TOT / 256) rowsum[row * 256 + tid] = 0.f;   // fold in memset

    const float4* p1 = (const float4*)(z1 + (size_t)row * Z_DIM);
    const float4* p2 = (const float4*)(z2 + (size_t)row * Z_DIM);
    float4 x0 = p1[tid * 2], x1 = p1[tid * 2 + 1];
    float4 y0 = p2[tid * 2], y1 = p2[tid * 2 + 1];

    float s1 = x0.x*x0.x + x0.y*x0.y + x0.z*x0.z + x0.w*x0.w
             + x1.x*x1.x + x1.y*x1.y + x1.z*x1.z + x1.w*x1.w;
    float s2 = y0.x*y0.x + y0.y*y0.y + y0.z*y0.z + y0.w*y0.w
             + y1.x*y1.x + y1.y*y1.y + y1.z*y1.z + y1.w*y1.w;
    float dd = x0.x*y0.x + x0.y*y0.y + x0.z*y0.z + x0.w*y0.w
             + x1.x*y1.x + x1.y*y1.y + x1.z*y1.z + x1.w*y1.w;

    #pragma unroll
    for (int m = 1; m < 64; m <<= 1) {
        s1 += __shfl_xor(s1, m);
        s2 += __shfl_xor(s2, m);
        dd += __shfl_xor(dd, m);
    }
    __shared__ float red[3][4];
    if (lane == 0) { red[0][wave] = s1; red[1][wave] = s2; red[2][wave] = dd; }
    __syncthreads();
    s1 = red[0][0] + red[0][1] + red[0][2] + red[0][3];
    s2 = red[1][0] + red[1][1] + red[1][2] + red[1][3];
    dd = red[2][0] + red[2][1] + red[2][2] + red[2][3];

    const float inv1 = rsqrtf(s1), inv2 = rsqrtf(s2);
    if (tid == 0) {
        float p = dd * inv1 * inv2 * INV_T;   // pos in full fp32 precision
        pos[row] = p;
        pos[row + N_ROWS] = p;
    }

    // fp4 encode of (normalized * 64): sigma ~1.4, range to ~6 (rare clip).
    // elem k -> byte k/2, LOW nibble = even k.
    const float a = inv1 * SCL4, b = inv2 * SCL4;
    unsigned int pa =  f2fp4(x0.x * a)        | (f2fp4(x0.y * a) << 4)
                    | (f2fp4(x0.z * a) << 8)  | (f2fp4(x0.w * a) << 12)
                    | (f2fp4(x1.x * a) << 16) | (f2fp4(x1.y * a) << 20)
                    | (f2fp4(x1.z * a) << 24) | (f2fp4(x1.w * a) << 28);
    unsigned int pb =  f2fp4(y0.x * b)        | (f2fp4(y0.y * b) << 4)
                    | (f2fp4(y0.z * b) << 8)  | (f2fp4(y0.w * b) << 12)
                    | (f2fp4(y1.x * b) << 16) | (f2fp4(y1.y * b) << 20)
                    | (f2fp4(y1.z * b) << 24) | (f2fp4(y1.w * b) << 28);
    *(unsigned int*)(reps + (size_t)row * RBYTES + tid * 4) = pa;
    *(unsigned int*)(reps + (size_t)(N_ROWS + row) * RBYTES + tid * 4) = pb;
}

// ---------------- kernel 2: triangular S = reps@reps^T, MX-fp4 K=128 --------
// Round-3 structure (128x128 tile, 2x2 waves, 4x4 grid of 16x16x128 f8f6f4
// MFMA, conflict-free (row>>1)&3 swizzle), with TWO changes:
//  (a) triple-buffered LDS (48 KiB, still 3 blocks/CU at 156 regs) and ONE
//      counted `s_waitcnt vmcnt(4)` + raw s_barrier per K-step -- next
//      step's 4 loads stay in flight across the barrier (no vmcnt(0) drain
//      mid-loop).  Hazard: stage at step i writes buf (i+2)%3 == buf
//      (i-1)%3, whose reads completed before this step's barrier.
//  (b) XCD-chunked blockIdx swizzle (2080 = 8 * 260, bijective): blocks
//      sharing a B panel run on the same XCD -> prefetches hit 4 MiB L2
//      (~200 cy) instead of LLC (~450 cy).
__global__ __launch_bounds__(256) void simclr_gemm(
    const unsigned char* __restrict__ reps, float* __restrict__ rowsum)
{
    __shared__ __align__(16) unsigned char L[3][2][TILE * KBYT];   // 48 KiB

    // XCD-aware chunked swizzle, then decode to lower-triangle (r >= c)
    const int bid = blockIdx.x;
    const int t = (bid & 7) * (NBLK / 8) + (bid >> 3);
    int r = (int)((sqrtf(8.0f * (float)t + 1.0f) - 1.0f) * 0.5f);
    while ((r + 1) * (r + 2) / 2 <= t) ++r;
    while (r * (r + 1) / 2 > t) --r;
    const int bi = t - r * (r + 1) / 2;   // <= bj
    const int bj = r;
    const bool diag = (bi == bj);

    const int tid  = threadIdx.x;
    const int lane = tid & 63, wave = tid >> 6;
    const int wr = wave >> 1, wc = wave & 1;       // 2x2 waves over 128x128
    const int quad = lane >> 4, l16 = lane & 15;
    const int sw   = (l16 >> 1) & 3;               // read-side XOR swizzle key
    const int row0 = bi * TILE, col0 = bj * TILE;

    floatx4 acc[4][4];
    #pragma unroll
    for (int i = 0; i < 4; ++i)
        #pragma unroll
        for (int j = 0; j < 4; ++j)
            acc[i][j] = floatx4{0.f, 0.f, 0.f, 0.f};

    // staging: 512 chunks of 16B per operand (128 rows x 4 chunks); thread
    // handles chunks tid and tid+256. LDS slot c holds global chunk
    // ((c&3) ^ (((c>>2)>>1)&3)) of row c>>2.
    const int c0 = tid, c1 = tid + 256;
    const int r0s = c0 >> 2, k0s = (c0 & 3) ^ ((r0s >> 1) & 3);
    const int r1s = c1 >> 2, k1s = (c1 & 3) ^ ((r1s >> 1) & 3);
    const unsigned char* gA0 = reps + (size_t)(row0 + r0s) * RBYTES + k0s * 16;
    const unsigned char* gA1 = reps + (size_t)(row0 + r1s) * RBYTES + k1s * 16;
    const unsigned char* gB0 = reps + (size_t)(col0 + r0s) * RBYTES + k0s * 16;
    const unsigned char* gB1 = reps + (size_t)(col0 + r1s) * RBYTES + k1s * 16;
    const int o0 = c0 * 16, o1 = c1 * 16;

    // prologue: steps 0,1 -> buffers 0,1 (8 loads/thread in flight)
    GLOAD16(gA0, &L[0][0][o0]);
    GLOAD16(gA1, &L[0][0][o1]);
    GLOAD16(gB0, &L[0][1][o0]);
    GLOAD16(gB1, &L[0][1][o1]);
    GLOAD16(gA0 + KBYT, &L[1][0][o0]);
    GLOAD16(gA1 + KBYT, &L[1][0][o1]);
    GLOAD16(gB0 + KBYT, &L[1][1][o0]);
    GLOAD16(gB1 + KBYT, &L[1][1][o1]);

    int cur = 0;
    #pragma unroll 1
    for (int i = 0; i < NITER; ++i) {
        // complete step i's 4 loads (oldest); leave step i+1's 4 in flight
        if (i + 1 < NITER) asm volatile("s_waitcnt vmcnt(4)" ::: "memory");
        else               asm volatile("s_waitcnt vmcnt(0)" ::: "memory");
        __builtin_amdgcn_s_barrier();
        asm volatile("" ::: "memory");

        if (i + 2 < NITER) {              // prefetch step i+2 into buf (i-1)%3
            const size_t ko = (size_t)(i + 2) * KBYT;
            int pf = cur + 2; if (pf >= 3) pf -= 3;
            GLOAD16(gA0 + ko, &L[pf][0][o0]);
            GLOAD16(gA1 + ko, &L[pf][0][o1]);
            GLOAD16(gB0 + ko, &L[pf][1][o0]);
            GLOAD16(gB1 + ko, &L[pf][1][o1]);
        }
        const unsigned char* Ab = &L[cur][0][0];
        const unsigned char* Bb = &L[cur][1][0];

        // fragment: 32 fp4 nibbles (elems k=quad*32..+32) = 16 B = 1 b128.
        // FMT=fp4 reads only v[0:3] of the 8-reg operand; upper half zero.
        intx8 af[4], bf[4];
        #pragma unroll
        for (int fi = 0; fi < 4; ++fi) {
            const int ar = (wr * 64 + fi * 16 + l16) * KBYT;
            const int br = (wc * 64 + fi * 16 + l16) * KBYT;
            intx4 av = *(const intx4*)&Ab[ar + ((quad ^ sw) << 4)];
            intx4 bv = *(const intx4*)&Bb[br + ((quad ^ sw) << 4)];
            af[fi] = intx8{av[0], av[1], av[2], av[3], 0, 0, 0, 0};
            bf[fi] = intx8{bv[0], bv[1], bv[2], bv[3], 0, 0, 0, 0};
        }
        __builtin_amdgcn_s_setprio(1);
        #pragma unroll
        for (int fi = 0; fi < 4; ++fi)
            #pragma unroll
            for (int j = 0; j < 4; ++j)
                acc[fi][j] = __builtin_amdgcn_mfma_scale_f32_16x16x128_f8f6f4(
                    af[fi], bf[j], acc[fi][j],
                    4, 4,                      // cbsz=fp4(A), blgp=fp4(B)
                    0, 0x7F7F7F7Fu,            // scale_a = 1.0 (E8M0)
                    0, 0x7F7F7F7Fu);           // scale_b = 1.0
        __builtin_amdgcn_s_setprio(0);
        cur = (cur == 2) ? 0 : cur + 1;
    }

    // Epilogue: C/D layout col = lane&15, row = quad*4 + reg.
    // logit = acc * INV_T / SCL4^2; |logit| <= 2 so plain exp-sum is safe.
    const float descale = INV_T / (SCL4 * SCL4);   // 1/2048
    float scol[4] = {0.f, 0.f, 0.f, 0.f};
    #pragma unroll
    for (int fi = 0; fi < 4; ++fi) {
        const int rbase = row0 + wr * 64 + fi * 16 + quad * 4;
        float srow[4] = {0.f, 0.f, 0.f, 0.f};
        #pragma unroll
        for (int j = 0; j < 4; ++j) {
            const int c = col0 + wc * 64 + j * 16 + l16;
            #pragma unroll
            for (int rr = 0; rr < 4; ++rr) {
                float e = __expf(acc[fi][j][rr] * descale);
                if (diag && (rbase + rr == c)) e = 0.f;  // exclude self-sim
                srow[rr] += e;
                scol[j]  += e;
            }
        }
        #pragma unroll
        for (int rr = 0; rr < 4; ++rr) {
            #pragma unroll
            for (int m = 1; m < 16; m <<= 1) srow[rr] += __shfl_xor(srow[rr], m);
        }
        if (l16 == 0) {
            #pragma unroll
            for (int rr = 0; rr < 4; ++rr)
                atomicAdd(&rowsum[rbase + rr], srow[rr]);
        }
    }
    if (!diag) {   // symmetry credit: column sums -> mirrored rows
        #pragma unroll
        for (int j = 0; j < 4; ++j) {
            scol[j] += __shfl_xor(scol[j], 16);
            scol[j] += __shfl_xor(scol[j], 32);
        }
        if (quad == 0) {
            #pragma unroll
            for (int j = 0; j < 4; ++j)
                atomicAdd(&rowsum[col0 + wc * 64 + j * 16 + l16], scol[j]);
        }
    }
}

// ---------------- kernel 3: mean(log(rowsum) - pos) ----------------
__global__ __launch_bounds__(1024) void finalize_kernel(
    const float* __restrict__ rowsum, const float* __restrict__ pos,
    float* __restrict__ out)
{
    const int tid = threadIdx.x;
    const int lane = tid & 63, wave = tid >> 6;
    float s = 0.f;
    for (int r = tid; r < TOT; r += 1024) s += logf(rowsum[r]) - pos[r];
    #pragma unroll
    for (int m = 1; m < 64; m <<= 1) s += __shfl_xor(s, m);
    __shared__ float red[16];
    if (lane == 0) red[wave] = s;
    __syncthreads();
    if (tid == 0) {
        float t = 0.f;
        #pragma unroll
        for (int w = 0; w < 16; ++w) t += red[w];
        out[0] = t * (1.0f / TOT);
    }
}

extern "C" void kernel_launch(void* const* d_in, const int* in_sizes, int n_in,
                              void* d_out, int out_size, void* d_ws, size_t ws_size,
                              hipStream_t stream)
{
    const float* z1 = (const float*)d_in[0];
    const float* z2 = (const float*)d_in[1];
    float* out = (float*)d_out;

    char* w = (char*)d_ws;
    unsigned char* reps = (unsigned char*)w;                 // 8 MiB fp4 [8192][1024B]
    float* pos    = (float*)(w + (size_t)TOT * RBYTES);      // 32 KiB
    float* rowsum = pos + TOT;                               // 32 KiB

    normalize_kernel<<<N_ROWS, 256, 0, stream>>>(z1, z2, reps, pos, rowsum);
    simclr_gemm<<<NBLK, 256, 0, stream>>>(reps, rowsum);
    finalize_kernel<<<1, 1024, 0, stream>>>(rowsum, pos, out);
}